// Round 3
// baseline (8955.893 us; speedup 1.0000x reference)
//
#include <hip/hip_runtime.h>
#include <cstdint>
#include <cstddef>

// ---------------- helpers ----------------

__device__ inline unsigned short f2bf(float f) {           // RNE f32->bf16
  union { float f; unsigned u; } a; a.f = f;
  unsigned r = a.u + 0x7fff + ((a.u >> 16) & 1);
  return (unsigned short)(r >> 16);
}
__device__ inline float bf2f(unsigned short u) {
  union { unsigned u; float f; } a; a.u = (unsigned)u << 16;
  return a.f;
}

// ---------------- small prep kernels ----------------

// WT[k*N + n] = W[n*K + k]   (W is N x K row-major, WT is K x N row-major)
__global__ void transpose_k(const float* __restrict__ W, float* __restrict__ WT,
                            int N, int K) {
  int i = blockIdx.x * blockDim.x + threadIdx.x;
  if (i < N * K) {
    int k = i / N, n = i - k * N;
    WT[i] = W[n * K + k];
  }
}

__global__ void count_k(const int* __restrict__ dst, float* __restrict__ cnt, int nE) {
  int i = blockIdx.x * blockDim.x + threadIdx.x;
  if (i < nE) atomicAdd(&cnt[dst[i]], 1.0f);
}

__global__ void inv_k(float* __restrict__ c, int n) {
  int i = blockIdx.x * blockDim.x + threadIdx.x;
  if (i < n) c[i] = 1.0f / fmaxf(c[i], 1.0f);
}

// ---------------- edge scatter (D = 128 floats / node) ----------------
// 32 lanes per edge, each lane one float4: gather coalesced, atomicAdd x4.
__global__ void scatter128_k(const float* __restrict__ x, const int* __restrict__ src,
                             const int* __restrict__ dst, float* __restrict__ agg,
                             int nE) {
  long long i = (long long)blockIdx.x * blockDim.x + threadIdx.x;
  if (i >= (long long)nE * 32) return;
  int e = (int)(i >> 5), q = (int)(i & 31);
  int s = src[e], d = dst[e];
  const float4 v = *((const float4*)(x + (size_t)s * 128) + q);
  float* p = agg + (size_t)d * 128 + (q << 2);
  atomicAdd(p + 0, v.x);
  atomicAdd(p + 1, v.y);
  atomicAdd(p + 2, v.z);
  atomicAdd(p + 3, v.w);
}

// ---------------- fused GEMM ----------------
// out[M x BN] = concat(A1*inv | A2)[M x (K1+K2)] @ WT[(K1+K2) x BN]
//               (+ bias) (+ add[row]*inv[row]) (+ ReLU)
// A1/add/bias/WT are f32. A2 is f32 or bf16 (A2BF). out is f32 or bf16 (OBF).
// Block computes BM rows x all BN cols. 256 threads, 8x8 micro-tile each.
template<int BM, int BN, int BK, bool RELU, bool A2BF, bool OBF>
__global__ __launch_bounds__(256) void gemm_cat(
    const float* __restrict__ A1, const float* __restrict__ inv,
    const void* __restrict__ A2v, const float* __restrict__ WT,
    const float* __restrict__ bias, const float* __restrict__ add,
    void* __restrict__ outv, int M, int K1, int K2) {
  constexpr int TM = 8, TN = 8, TX = BN / TN, TY = BM / TM;
  static_assert(TX * TY == 256, "need 256 threads");
  __shared__ float As[BK][BM];   // transposed A tile
  __shared__ float Ws[BK][BN];

  const int tid = threadIdx.x;
  const int tx = tid % TX, ty = tid / TX;
  const int row0 = blockIdx.x * BM;
  const int Ktot = K1 + K2;

  float acc[TM][TN];
#pragma unroll
  for (int i = 0; i < TM; i++)
#pragma unroll
    for (int j = 0; j < TN; j++) acc[i][j] = 0.f;

  for (int k0 = 0; k0 < Ktot; k0 += BK) {
    // stage A tile (BM x BK), 4 elems along K per thread-step, store transposed
    constexpr int AQ = BM * (BK / 4);
#pragma unroll
    for (int q = tid; q < AQ; q += 256) {
      int m = q / (BK / 4), kq = q % (BK / 4);
      int row = row0 + m;
      if (row >= M) row = M - 1;
      int k = k0 + kq * 4;
      float4 v;
      if (k < K1) {
        v = *(const float4*)(A1 + (size_t)row * K1 + k);
        float s = inv[row];
        v.x *= s; v.y *= s; v.z *= s; v.w *= s;
      } else {
        if (A2BF) {
          const ushort4 u = *(const ushort4*)((const unsigned short*)A2v +
                                              (size_t)row * K2 + (k - K1));
          v.x = bf2f(u.x); v.y = bf2f(u.y); v.z = bf2f(u.z); v.w = bf2f(u.w);
        } else {
          v = *(const float4*)((const float*)A2v + (size_t)row * K2 + (k - K1));
        }
      }
      As[kq * 4 + 0][m] = v.x;
      As[kq * 4 + 1][m] = v.y;
      As[kq * 4 + 2][m] = v.z;
      As[kq * 4 + 3][m] = v.w;
    }
    // stage W tile (BK x BN), direct float4 copy
    constexpr int WQ = BK * (BN / 4);
#pragma unroll
    for (int q = tid; q < WQ; q += 256) {
      int k = q / (BN / 4), nq = q % (BN / 4);
      *(float4*)&Ws[k][nq * 4] = *(const float4*)(WT + (size_t)(k0 + k) * BN + nq * 4);
    }
    __syncthreads();
#pragma unroll
    for (int kk = 0; kk < BK; ++kk) {
      float a[TM], w[TN];
      *(float4*)&a[0] = *(const float4*)&As[kk][ty * TM];
      *(float4*)&a[4] = *(const float4*)&As[kk][ty * TM + 4];
      *(float4*)&w[0] = *(const float4*)&Ws[kk][tx * TN];
      *(float4*)&w[4] = *(const float4*)&Ws[kk][tx * TN + 4];
#pragma unroll
      for (int i = 0; i < TM; i++)
#pragma unroll
        for (int j = 0; j < TN; j++) acc[i][j] = fmaf(a[i], w[j], acc[i][j]);
    }
    __syncthreads();
  }

#pragma unroll
  for (int i = 0; i < TM; i++) {
    int row = row0 + ty * TM + i;
    if (row < M) {
      float sc = (add != nullptr) ? inv[row] : 0.f;
#pragma unroll
      for (int j = 0; j < TN; j += 4) {
        int n = tx * TN + j;
        float4 v = {acc[i][j], acc[i][j + 1], acc[i][j + 2], acc[i][j + 3]};
        if (bias) {
          v.x += bias[n + 0]; v.y += bias[n + 1];
          v.z += bias[n + 2]; v.w += bias[n + 3];
        }
        if (add) {
          const float4 ad = *(const float4*)(add + (size_t)row * BN + n);
          v.x += ad.x * sc; v.y += ad.y * sc; v.z += ad.z * sc; v.w += ad.w * sc;
        }
        if (RELU) {
          v.x = fmaxf(v.x, 0.f); v.y = fmaxf(v.y, 0.f);
          v.z = fmaxf(v.z, 0.f); v.w = fmaxf(v.w, 0.f);
        }
        if (OBF) {
          ushort4 u = {f2bf(v.x), f2bf(v.y), f2bf(v.z), f2bf(v.w)};
          *(ushort4*)((unsigned short*)outv + (size_t)row * BN + n) = u;
        } else {
          *(float4*)((float*)outv + (size_t)row * BN + n) = v;
        }
      }
    }
  }
}

// ---------------- launch ----------------
// d_ws budget (~412 MB): cnt (1.6MB) + WT (1MB) + h bf16 (204.8MB) + agg2 f32
// (204.8MB). agg1 and z live in d_out (dead before outputs are written).

extern "C" void kernel_launch(void* const* d_in, const int* in_sizes, int n_in,
                              void* d_out, int out_size, void* d_ws, size_t ws_size,
                              hipStream_t stream) {
  const float* x_user = (const float*)d_in[0];
  const float* x_item = (const float*)d_in[1];
  const int* e_u2i = (const int*)d_in[2];
  const int* e_i2u = (const int*)d_in[3];
  const float* Wl1_ui = (const float*)d_in[4];
  const float* Wr1_ui = (const float*)d_in[5];
  const float* b1_ui  = (const float*)d_in[6];
  const float* Wl1_iu = (const float*)d_in[7];
  const float* Wr1_iu = (const float*)d_in[8];
  const float* b1_iu  = (const float*)d_in[9];
  const float* Wl2_ui = (const float*)d_in[10];
  const float* Wr2_ui = (const float*)d_in[11];
  const float* b2_ui  = (const float*)d_in[12];
  const float* Wl2_iu = (const float*)d_in[13];
  const float* Wr2_iu = (const float*)d_in[14];
  const float* b2_iu  = (const float*)d_in[15];

  const int NU = in_sizes[0] / 128;
  const int NI = in_sizes[1] / 128;
  const int NE = in_sizes[2] / 2;

  float* ws = (float*)d_ws;
  size_t o = 0;
  auto alloc = [&](size_t nfloats) {
    size_t r = o; o += (nfloats + 63) & ~(size_t)63; return r;
  };

  float* cnt_item = ws + alloc(NI);            // becomes inv after inv_k
  float* cnt_user = ws + alloc(NU);
  float* WT1_ui  = ws + alloc(256 * 256);
  float* WT1_iu  = ws + alloc(256 * 256);
  float* WT2l_ui = ws + alloc(256 * 128);
  float* WT2r_ui = ws + alloc(256 * 128);
  float* WT2l_iu = ws + alloc(256 * 128);
  float* WT2r_iu = ws + alloc(256 * 128);
  unsigned short* h_item = (unsigned short*)(ws + alloc((size_t)NI * 128)); // NI*256 bf16
  unsigned short* h_user = (unsigned short*)(ws + alloc((size_t)NU * 128)); // NU*256 bf16
  float* agg2_item = ws + alloc((size_t)NI * 128);
  float* agg2_user = ws + alloc((size_t)NU * 128);

  float* o_user = (float*)d_out;                       // NU*128
  float* o_item = (float*)d_out + (size_t)NU * 128;    // NI*128

  // d_out doubles as scratch: layer-1 aggregators, then z = h @ Wl2^T
  float* agg1_item = o_item;
  float* agg1_user = o_user;
  float* z_u2i = o_user;   // NU rows x 128
  float* z_i2u = o_item;   // NI rows x 128

  // zero accumulators / counters (d_out is poisoned 0xAA before timed runs)
  hipMemsetAsync(cnt_item, 0, (size_t)(NI + 64 + NU) * 4, stream);
  hipMemsetAsync(d_out, 0, (size_t)(NU + NI) * 128 * 4, stream);
  hipMemsetAsync(agg2_item, 0, ((size_t)NI + NU) * 128 * 4, stream);

  // weight transposes (tiny)
  transpose_k<<<128, 256, 0, stream>>>(Wl1_ui, WT1_ui, 256, 128);
  transpose_k<<<128, 256, 0, stream>>>(Wr1_ui, WT1_ui + 128 * 256, 256, 128);
  transpose_k<<<128, 256, 0, stream>>>(Wl1_iu, WT1_iu, 256, 128);
  transpose_k<<<128, 256, 0, stream>>>(Wr1_iu, WT1_iu + 128 * 256, 256, 128);
  transpose_k<<<128, 256, 0, stream>>>(Wl2_ui, WT2l_ui, 128, 256);
  transpose_k<<<128, 256, 0, stream>>>(Wr2_ui, WT2r_ui, 128, 256);
  transpose_k<<<128, 256, 0, stream>>>(Wl2_iu, WT2l_iu, 128, 256);
  transpose_k<<<128, 256, 0, stream>>>(Wr2_iu, WT2r_iu, 128, 256);

  // degree counts -> inverse
  int cgrid = (NE + 255) / 256;
  count_k<<<cgrid, 256, 0, stream>>>(e_u2i + NE, cnt_item, NE);
  count_k<<<cgrid, 256, 0, stream>>>(e_i2u + NE, cnt_user, NE);
  inv_k<<<(NI + 255) / 256, 256, 0, stream>>>(cnt_item, NI);
  inv_k<<<(NU + 255) / 256, 256, 0, stream>>>(cnt_user, NU);

  // layer 1 aggregation (aggregate-first: 128-dim), into d_out regions
  int sgrid = (int)(((long long)NE * 32 + 255) / 256);
  scatter128_k<<<sgrid, 256, 0, stream>>>(x_user, e_u2i, e_u2i + NE, agg1_item, NE);
  scatter128_k<<<sgrid, 256, 0, stream>>>(x_item, e_i2u, e_i2u + NE, agg1_user, NE);

  // layer 1 GEMMs: h = ReLU([mean|x] @ [Wl;Wr]^T + b), h stored bf16
  gemm_cat<64, 256, 32, true, false, true><<<(NI + 63) / 64, 256, 0, stream>>>(
      agg1_item, cnt_item, x_item, WT1_ui, b1_ui, nullptr, h_item, NI, 128, 128);
  gemm_cat<64, 256, 32, true, false, true><<<(NU + 63) / 64, 256, 0, stream>>>(
      agg1_user, cnt_user, x_user, WT1_iu, b1_iu, nullptr, h_user, NU, 128, 128);

  // layer 2 transform-first: z = h @ Wl2^T (128-dim messages), into d_out
  gemm_cat<128, 128, 32, false, true, false><<<(NU + 127) / 128, 256, 0, stream>>>(
      nullptr, nullptr, h_user, WT2l_ui, nullptr, nullptr, z_u2i, NU, 0, 256);
  gemm_cat<128, 128, 32, false, true, false><<<(NI + 127) / 128, 256, 0, stream>>>(
      nullptr, nullptr, h_item, WT2l_iu, nullptr, nullptr, z_i2u, NI, 0, 256);

  // layer 2 aggregation
  scatter128_k<<<sgrid, 256, 0, stream>>>(z_u2i, e_u2i, e_u2i + NE, agg2_item, NE);
  scatter128_k<<<sgrid, 256, 0, stream>>>(z_i2u, e_i2u, e_i2u + NE, agg2_user, NE);

  // layer 2 output GEMMs: o = h_dst @ Wr2^T + b + agg2*inv  (overwrites z)
  gemm_cat<128, 128, 32, false, true, false><<<(NI + 127) / 128, 256, 0, stream>>>(
      nullptr, cnt_item, h_item, WT2r_ui, b2_ui, agg2_item, o_item, NI, 0, 256);
  gemm_cat<128, 128, 32, false, true, false><<<(NU + 127) / 128, 256, 0, stream>>>(
      nullptr, cnt_user, h_user, WT2r_iu, b2_iu, agg2_user, o_user, NU, 0, 256);
}

// Round 4
// 3189.116 us; speedup vs baseline: 2.8083x; 2.8083x over previous
//
#include <hip/hip_runtime.h>
#include <cstdint>
#include <cstddef>

// ---------------- helpers ----------------

__device__ inline unsigned short f2bf(float f) {           // RNE f32->bf16
  union { float f; unsigned u; } a; a.f = f;
  unsigned r = a.u + 0x7fff + ((a.u >> 16) & 1);
  return (unsigned short)(r >> 16);
}
__device__ inline float bf2f(unsigned short u) {
  union { unsigned u; float f; } a; a.u = (unsigned)u << 16;
  return a.f;
}

// ---------------- small prep kernels ----------------

// WT[k*N + n] = W[n*K + k]   (W is N x K row-major, WT is K x N row-major)
__global__ void transpose_k(const float* __restrict__ W, float* __restrict__ WT,
                            int N, int K) {
  int i = blockIdx.x * blockDim.x + threadIdx.x;
  if (i < N * K) {
    int k = i / N, n = i - k * N;
    WT[i] = W[n * K + k];
  }
}

// f32 -> bf16, 4 elems/thread
__global__ void cvt_k(const float* __restrict__ in, unsigned short* __restrict__ out,
                      int n4) {
  int i = blockIdx.x * blockDim.x + threadIdx.x;
  if (i < n4) {
    float4 v = ((const float4*)in)[i];
    ushort4 u = {f2bf(v.x), f2bf(v.y), f2bf(v.z), f2bf(v.w)};
    ((ushort4*)out)[i] = u;
  }
}

__global__ void hist_k(const int* __restrict__ dst, int* __restrict__ cnt, int nE) {
  int i = blockIdx.x * blockDim.x + threadIdx.x;
  if (i < nE) atomicAdd(&cnt[dst[i]], 1);
}

// single-block exclusive scan: cnt[0..n) -> rowptr[0..n], rowptr[n]=total
__global__ __launch_bounds__(1024) void scan_k(const int* __restrict__ cnt,
                                               int* __restrict__ rowptr, int n) {
  __shared__ int ssum[1024];
  int t = threadIdx.x;
  int chunk = (n + 1023) >> 10;
  int beg = t * chunk, end = beg + chunk;
  if (end > n) end = n;
  int s = 0;
  for (int i = beg; i < end; i++) s += cnt[i];
  ssum[t] = s;
  __syncthreads();
  for (int off = 1; off < 1024; off <<= 1) {
    int v = (t >= off) ? ssum[t - off] : 0;
    __syncthreads();
    ssum[t] += v;
    __syncthreads();
  }
  int excl = (t == 0) ? 0 : ssum[t - 1];
  for (int i = beg; i < end; i++) {
    rowptr[i] = excl;
    excl += cnt[i];
  }
  if (t == 1023) rowptr[n] = ssum[1023];
}

// scatter src ids into CSR order
__global__ void fill_k(const int* __restrict__ src, const int* __restrict__ dst,
                       const int* __restrict__ rowptr, int* __restrict__ cur,
                       int* __restrict__ srcs, int nE) {
  int i = blockIdx.x * blockDim.x + threadIdx.x;
  if (i < nE) {
    int d = dst[i];
    int p = rowptr[d] + atomicAdd(&cur[d], 1);
    srcs[p] = src[i];
  }
}

// ---------------- CSR mean-aggregation (no atomics) ----------------
// one wave per dst node; lane handles 2 bf16 (row = 128 bf16 = 256B coalesced)
__global__ void agg_csr_k(const unsigned short* __restrict__ xb,
                          const int* __restrict__ rowptr,
                          const int* __restrict__ srcs,
                          unsigned short* __restrict__ mean, int nDst) {
  int w = blockIdx.x * (blockDim.x >> 6) + (threadIdx.x >> 6);
  int lane = threadIdx.x & 63;
  if (w >= nDst) return;
  int beg = rowptr[w], end = rowptr[w + 1];
  float ax = 0.f, ay = 0.f;
  for (int e = beg; e < end; e++) {
    int s = srcs[e];
    unsigned u = *((const unsigned*)(xb + (size_t)s * 128) + lane);
    ax += bf2f((unsigned short)(u & 0xffff));
    ay += bf2f((unsigned short)(u >> 16));
  }
  float inv = 1.f / fmaxf((float)(end - beg), 1.f);
  unsigned short lo = f2bf(ax * inv), hi = f2bf(ay * inv);
  *((unsigned*)(mean + (size_t)w * 128) + lane) = ((unsigned)hi << 16) | lo;
}

// ---------------- fused GEMM (bf16 A, f32 W/accum) ----------------
// out[M x BN] = concat(A1 | A2)[M x (K1+K2)] @ WT[(K1+K2) x BN]
//               (+ bias) (+ add[row], bf16) (+ ReLU); out f32 or bf16
template<int BM, int BN, int BK, bool RELU, bool OBF>
__global__ __launch_bounds__(256) void gemm_cat(
    const unsigned short* __restrict__ A1, const unsigned short* __restrict__ A2,
    const float* __restrict__ WT, const float* __restrict__ bias,
    const unsigned short* __restrict__ add, void* __restrict__ outv,
    int M, int K1, int K2) {
  constexpr int TM = 8, TN = 8, TX = BN / TN, TY = BM / TM;
  static_assert(TX * TY == 256, "need 256 threads");
  __shared__ float As[BK][BM];   // transposed A tile
  __shared__ float Ws[BK][BN];

  const int tid = threadIdx.x;
  const int tx = tid % TX, ty = tid / TX;
  const int row0 = blockIdx.x * BM;
  const int Ktot = K1 + K2;

  float acc[TM][TN];
#pragma unroll
  for (int i = 0; i < TM; i++)
#pragma unroll
    for (int j = 0; j < TN; j++) acc[i][j] = 0.f;

  for (int k0 = 0; k0 < Ktot; k0 += BK) {
    constexpr int AQ = BM * (BK / 4);
#pragma unroll
    for (int q = tid; q < AQ; q += 256) {
      int m = q / (BK / 4), kq = q % (BK / 4);
      int row = row0 + m;
      if (row >= M) row = M - 1;
      int k = k0 + kq * 4;
      ushort4 u;
      if (k < K1) u = *(const ushort4*)(A1 + (size_t)row * K1 + k);
      else        u = *(const ushort4*)(A2 + (size_t)row * K2 + (k - K1));
      As[kq * 4 + 0][m] = bf2f(u.x);
      As[kq * 4 + 1][m] = bf2f(u.y);
      As[kq * 4 + 2][m] = bf2f(u.z);
      As[kq * 4 + 3][m] = bf2f(u.w);
    }
    constexpr int WQ = BK * (BN / 4);
#pragma unroll
    for (int q = tid; q < WQ; q += 256) {
      int k = q / (BN / 4), nq = q % (BN / 4);
      *(float4*)&Ws[k][nq * 4] = *(const float4*)(WT + (size_t)(k0 + k) * BN + nq * 4);
    }
    __syncthreads();
#pragma unroll
    for (int kk = 0; kk < BK; ++kk) {
      float a[TM], w[TN];
      *(float4*)&a[0] = *(const float4*)&As[kk][ty * TM];
      *(float4*)&a[4] = *(const float4*)&As[kk][ty * TM + 4];
      *(float4*)&w[0] = *(const float4*)&Ws[kk][tx * TN];
      *(float4*)&w[4] = *(const float4*)&Ws[kk][tx * TN + 4];
#pragma unroll
      for (int i = 0; i < TM; i++)
#pragma unroll
        for (int j = 0; j < TN; j++) acc[i][j] = fmaf(a[i], w[j], acc[i][j]);
    }
    __syncthreads();
  }

#pragma unroll
  for (int i = 0; i < TM; i++) {
    int row = row0 + ty * TM + i;
    if (row < M) {
#pragma unroll
      for (int j = 0; j < TN; j += 4) {
        int n = tx * TN + j;
        float4 v = {acc[i][j], acc[i][j + 1], acc[i][j + 2], acc[i][j + 3]};
        if (bias) {
          v.x += bias[n + 0]; v.y += bias[n + 1];
          v.z += bias[n + 2]; v.w += bias[n + 3];
        }
        if (add) {
          const ushort4 ad = *(const ushort4*)(add + (size_t)row * BN + n);
          v.x += bf2f(ad.x); v.y += bf2f(ad.y);
          v.z += bf2f(ad.z); v.w += bf2f(ad.w);
        }
        if (RELU) {
          v.x = fmaxf(v.x, 0.f); v.y = fmaxf(v.y, 0.f);
          v.z = fmaxf(v.z, 0.f); v.w = fmaxf(v.w, 0.f);
        }
        if (OBF) {
          ushort4 u = {f2bf(v.x), f2bf(v.y), f2bf(v.z), f2bf(v.w)};
          *(ushort4*)((unsigned short*)outv + (size_t)row * BN + n) = u;
        } else {
          *(float4*)((float*)outv + (size_t)row * BN + n) = v;
        }
      }
    }
  }
}

// ---------------- launch ----------------
// ws (~320 MB): CSR ints (~11.4MB) + WT (~1MB) + h bf16 (204.8MB) + agg2 bf16
// (102.4MB). xb / agg1 / z live in d_out (dead before final GEMMs write it).

extern "C" void kernel_launch(void* const* d_in, const int* in_sizes, int n_in,
                              void* d_out, int out_size, void* d_ws, size_t ws_size,
                              hipStream_t stream) {
  const float* x_user = (const float*)d_in[0];
  const float* x_item = (const float*)d_in[1];
  const int* e_u2i = (const int*)d_in[2];
  const int* e_i2u = (const int*)d_in[3];
  const float* Wl1_ui = (const float*)d_in[4];
  const float* Wr1_ui = (const float*)d_in[5];
  const float* b1_ui  = (const float*)d_in[6];
  const float* Wl1_iu = (const float*)d_in[7];
  const float* Wr1_iu = (const float*)d_in[8];
  const float* b1_iu  = (const float*)d_in[9];
  const float* Wl2_ui = (const float*)d_in[10];
  const float* Wr2_ui = (const float*)d_in[11];
  const float* b2_ui  = (const float*)d_in[12];
  const float* Wl2_iu = (const float*)d_in[13];
  const float* Wr2_iu = (const float*)d_in[14];
  const float* b2_iu  = (const float*)d_in[15];

  const int NU = in_sizes[0] / 128;
  const int NI = in_sizes[1] / 128;
  const int NE = in_sizes[2] / 2;

  char* ws = (char*)d_ws;
  size_t o = 0;
  auto alloc = [&](size_t bytes) {
    size_t r = o; o += (bytes + 255) & ~(size_t)255; return r;
  };

  int* rp_item = (int*)(ws + alloc((size_t)(NI + 1) * 4));  // CSR rowptr (u2i)
  int* rp_user = (int*)(ws + alloc((size_t)(NU + 1) * 4));  // CSR rowptr (i2u)
  int* cur_item = (int*)(ws + alloc((size_t)NI * 4));       // hist, then cursor
  int* cur_user = (int*)(ws + alloc((size_t)NU * 4));
  int* srcs_u2i = (int*)(ws + alloc((size_t)NE * 4));       // user ids, CSR order
  int* srcs_i2u = (int*)(ws + alloc((size_t)NE * 4));       // item ids, CSR order
  float* WT1_ui  = (float*)(ws + alloc(256 * 256 * 4));
  float* WT1_iu  = (float*)(ws + alloc(256 * 256 * 4));
  float* WT2l_ui = (float*)(ws + alloc(256 * 128 * 4));
  float* WT2r_ui = (float*)(ws + alloc(256 * 128 * 4));
  float* WT2l_iu = (float*)(ws + alloc(256 * 128 * 4));
  float* WT2r_iu = (float*)(ws + alloc(256 * 128 * 4));
  unsigned short* h_item = (unsigned short*)(ws + alloc((size_t)NI * 256 * 2));
  unsigned short* h_user = (unsigned short*)(ws + alloc((size_t)NU * 256 * 2));
  unsigned short* agg2_item = (unsigned short*)(ws + alloc((size_t)NI * 128 * 2));
  unsigned short* agg2_user = (unsigned short*)(ws + alloc((size_t)NU * 128 * 2));

  // d_out scratch (stream-ordered, dead before final GEMMs):
  //   xb   at [0, (NU+NI)*256B)          agg1 after it          z over xb later
  unsigned short* xb_user = (unsigned short*)d_out;
  unsigned short* xb_item = xb_user + (size_t)NU * 128;
  unsigned short* agg1_item = xb_item + (size_t)NI * 128;
  unsigned short* agg1_user = agg1_item + (size_t)NI * 128;
  unsigned short* z_u2i = (unsigned short*)d_out;            // NU rows (over xb)
  unsigned short* z_i2u = z_u2i + (size_t)NU * 128;          // NI rows

  float* o_user = (float*)d_out;                       // NU*128 f32
  float* o_item = (float*)d_out + (size_t)NU * 128;    // NI*128 f32

  // weight transposes (tiny)
  transpose_k<<<128, 256, 0, stream>>>(Wl1_ui, WT1_ui, 256, 128);
  transpose_k<<<128, 256, 0, stream>>>(Wr1_ui, WT1_ui + 128 * 256, 256, 128);
  transpose_k<<<128, 256, 0, stream>>>(Wl1_iu, WT1_iu, 256, 128);
  transpose_k<<<128, 256, 0, stream>>>(Wr1_iu, WT1_iu + 128 * 256, 256, 128);
  transpose_k<<<128, 256, 0, stream>>>(Wl2_ui, WT2l_ui, 128, 256);
  transpose_k<<<128, 256, 0, stream>>>(Wr2_ui, WT2r_ui, 128, 256);
  transpose_k<<<128, 256, 0, stream>>>(Wl2_iu, WT2l_iu, 128, 256);
  transpose_k<<<128, 256, 0, stream>>>(Wr2_iu, WT2r_iu, 128, 256);

  // x -> bf16 (into d_out scratch)
  cvt_k<<<(NU * 32 + 255) / 256, 256, 0, stream>>>(x_user, xb_user, NU * 32);
  cvt_k<<<(NI * 32 + 255) / 256, 256, 0, stream>>>(x_item, xb_item, NI * 32);

  // ---- CSR build (both directions), reused by both layers ----
  int egrid = (NE + 255) / 256;
  hipMemsetAsync(cur_item, 0, (size_t)(NI + NU) * 4 + 256, stream);  // contiguous pair
  hist_k<<<egrid, 256, 0, stream>>>(e_u2i + NE, cur_item, NE);
  hist_k<<<egrid, 256, 0, stream>>>(e_i2u + NE, cur_user, NE);
  scan_k<<<1, 1024, 0, stream>>>(cur_item, rp_item, NI);
  scan_k<<<1, 1024, 0, stream>>>(cur_user, rp_user, NU);
  hipMemsetAsync(cur_item, 0, (size_t)(NI + NU) * 4 + 256, stream);
  fill_k<<<egrid, 256, 0, stream>>>(e_u2i, e_u2i + NE, rp_item, cur_item, srcs_u2i, NE);
  fill_k<<<egrid, 256, 0, stream>>>(e_i2u, e_i2u + NE, rp_user, cur_user, srcs_i2u, NE);

  // ---- layer 1: mean aggregation (gather, no atomics) ----
  agg_csr_k<<<(NI + 3) / 4, 256, 0, stream>>>(xb_user, rp_item, srcs_u2i,
                                              agg1_item, NI);
  agg_csr_k<<<(NU + 3) / 4, 256, 0, stream>>>(xb_item, rp_user, srcs_i2u,
                                              agg1_user, NU);

  // layer 1 GEMMs: h = ReLU([mean|x] @ [Wl;Wr]^T + b), h bf16
  gemm_cat<64, 256, 32, true, true><<<(NI + 63) / 64, 256, 0, stream>>>(
      agg1_item, xb_item, WT1_ui, b1_ui, nullptr, h_item, NI, 128, 128);
  gemm_cat<64, 256, 32, true, true><<<(NU + 63) / 64, 256, 0, stream>>>(
      agg1_user, xb_user, WT1_iu, b1_iu, nullptr, h_user, NU, 128, 128);

  // ---- layer 2 transform-first: z = h @ Wl2^T (bf16, into d_out) ----
  gemm_cat<128, 128, 32, false, true><<<(NU + 127) / 128, 256, 0, stream>>>(
      nullptr, h_user, WT2l_ui, nullptr, nullptr, z_u2i, NU, 0, 256);
  gemm_cat<128, 128, 32, false, true><<<(NI + 127) / 128, 256, 0, stream>>>(
      nullptr, h_item, WT2l_iu, nullptr, nullptr, z_i2u, NI, 0, 256);

  // layer 2 mean aggregation
  agg_csr_k<<<(NI + 3) / 4, 256, 0, stream>>>(z_u2i, rp_item, srcs_u2i,
                                              agg2_item, NI);
  agg_csr_k<<<(NU + 3) / 4, 256, 0, stream>>>(z_i2u, rp_user, srcs_i2u,
                                              agg2_user, NU);

  // layer 2 output GEMMs: o = h_dst @ Wr2^T + b + agg2   (f32 into d_out)
  gemm_cat<128, 128, 32, false, false><<<(NI + 127) / 128, 256, 0, stream>>>(
      nullptr, h_item, WT2r_ui, b2_ui, agg2_item, o_item, NI, 0, 256);
  gemm_cat<128, 128, 32, false, false><<<(NU + 127) / 128, 256, 0, stream>>>(
      nullptr, h_user, WT2r_iu, b2_iu, agg2_user, o_user, NU, 0, 256);
}